// Round 1
// 385.757 us; speedup vs baseline: 1.0661x; 1.0661x over previous
//
#include <hip/hip_runtime.h>
#include <hip/hip_bf16.h>

typedef __hip_bfloat16 bf16;
typedef __attribute__((ext_vector_type(8))) short short8;
typedef __attribute__((ext_vector_type(4))) float floatx4;

#define L_SZ 8192
#define HFS 8194        // hf row stride in float2 (pair-layout, 16B-aligned rows)
#define PD2(i) ((i) + (((i) >> 4) << 1))   // float2 LDS pad: +2 per 16 (keeps pairs 16B-aligned)
#define SWZ(row, col) ((row) * 64 + ((col) ^ (((row) & 7) * 8)))   // GEMM LDS swizzle
#define ANGN 3.83495197e-4f    // 2*pi/16384

// twiddle table layout (float2 units) — lives in d_out scratch (overwritten by gemm_out_k at end)
#define TW0 0        // M=8192, k=0..1023, 8 powers each
#define TW1 8192     // M=1024, k=0..127
#define TW2 9216     // M=128,  k=0..15
#define TW3 9344     // M=16,   k=0..1
#define OTB 9360     // orbit untangle twiddles, indexed by storage p, 2304 entries
#define HF_BYTE_OFF 131072   // hf region offset within d_out

__device__ __forceinline__ float b2f(bf16 x) { return __bfloat162float(x); }
__device__ __forceinline__ bf16 f2b(float x) { return __float2bfloat16(x); }
__device__ __forceinline__ float lo2f(unsigned int u) { return __uint_as_float(u << 16); }
__device__ __forceinline__ float hi2f(unsigned int u) { return __uint_as_float(u & 0xffff0000u); }
__device__ __forceinline__ unsigned short f2bu(float x) {
    bf16 b = __float2bfloat16(x);
    return *reinterpret_cast<unsigned short*>(&b);
}
__device__ __forceinline__ short f2bs(float x) {
    bf16 b = __float2bfloat16(x);
    return *reinterpret_cast<short*>(&b);
}
__device__ __forceinline__ short8 pack8(float4 a, float4 b) {
    short8 r;
    r[0] = f2bs(a.x); r[1] = f2bs(a.y); r[2] = f2bs(a.z); r[3] = f2bs(a.w);
    r[4] = f2bs(b.x); r[5] = f2bs(b.y); r[6] = f2bs(b.z); r[7] = f2bs(b.w);
    return r;
}

// half-perm: storage position pair-base of frequency q (q<4096) after DIF [8,8,8,8,(2)]
__device__ __forceinline__ int P2h(int k) {
    return ((k & 7) << 9) | (((k >> 3) & 7) << 6) | (((k >> 6) & 7) << 3) | ((k >> 9) & 7);
}

// ---------------------------------------------------------------------------
// 8-point DFT, SF=-1 forward, SF=+1 inverse
// ---------------------------------------------------------------------------
template<int SF>
__device__ __forceinline__ void dft8(const float xr[8], const float xi[8],
                                     float yr[8], float yi[8]) {
    constexpr float sgn = (SF < 0) ? -1.f : 1.f;
    const float S2 = 0.70710678118654752f;
    float t0r=xr[0]+xr[4], t0i=xi[0]+xi[4];
    float t1r=xr[0]-xr[4], t1i=xi[0]-xi[4];
    float t2r=xr[2]+xr[6], t2i=xi[2]+xi[6];
    float t3r=xr[2]-xr[6], t3i=xi[2]-xi[6];
    float u0r=xr[1]+xr[5], u0i=xi[1]+xi[5];
    float u1r=xr[1]-xr[5], u1i=xi[1]-xi[5];
    float u2r=xr[3]+xr[7], u2i=xi[3]+xi[7];
    float u3r=xr[3]-xr[7], u3i=xi[3]-xi[7];
    float m3r = -sgn*t3i, m3i = sgn*t3r;
    float n3r = -sgn*u3i, n3i = sgn*u3r;
    float E0r=t0r+t2r, E0i=t0i+t2i, E2r=t0r-t2r, E2i=t0i-t2i;
    float E1r=t1r+m3r, E1i=t1i+m3i, E3r=t1r-m3r, E3i=t1i-m3i;
    float O0r=u0r+u2r, O0i=u0i+u2i, O2r=u0r-u2r, O2i=u0i-u2i;
    float O1r=u1r+n3r, O1i=u1i+n3i, O3r=u1r-n3r, O3i=u1i-n3i;
    float a1r = S2*(O1r - sgn*O1i),  a1i = S2*(O1i + sgn*O1r);
    float a2r = -sgn*O2i,            a2i = sgn*O2r;
    float a3r = S2*(-O3r - sgn*O3i), a3i = S2*(sgn*O3r - O3i);
    yr[0]=E0r+O0r; yi[0]=E0i+O0i; yr[4]=E0r-O0r; yi[4]=E0i-O0i;
    yr[1]=E1r+a1r; yi[1]=E1i+a1i; yr[5]=E1r-a1r; yi[5]=E1i-a1i;
    yr[2]=E2r+a2r; yi[2]=E2i+a2i; yr[6]=E2r-a2r; yi[6]=E2i-a2i;
    yr[3]=E3r+a3r; yi[3]=E3i+a3i; yr[7]=E3r-a3r; yi[7]=E3i-a3i;
}

// apply table twiddles w^j (forward table holds e^{-i*j*theta}) to y[1..7]
__device__ __forceinline__ void twmul_fwd(const float2* __restrict__ w8, float yr[8], float yi[8]) {
    float4 w01 = *(const float4*)(w8);
    float4 w23 = *(const float4*)(w8 + 2);
    float4 w45 = *(const float4*)(w8 + 4);
    float4 w67 = *(const float4*)(w8 + 6);
    float wr[8], wi[8];
    wr[1]=w01.z; wi[1]=w01.w; wr[2]=w23.x; wi[2]=w23.y; wr[3]=w23.z; wi[3]=w23.w;
    wr[4]=w45.x; wi[4]=w45.y; wr[5]=w45.z; wi[5]=w45.w; wr[6]=w67.x; wi[6]=w67.y; wr[7]=w67.z; wi[7]=w67.w;
#pragma unroll
    for (int j = 1; j < 8; ++j) {
        float a = yr[j], b = yi[j];
        yr[j] = fmaf(a, wr[j], -b * wi[j]);
        yi[j] = fmaf(a, wi[j],  b * wr[j]);
    }
}
// conjugate (inverse) application of the same forward table
__device__ __forceinline__ void twmul_inv(const float2* __restrict__ w8, float yr[8], float yi[8]) {
    float4 w01 = *(const float4*)(w8);
    float4 w23 = *(const float4*)(w8 + 2);
    float4 w45 = *(const float4*)(w8 + 4);
    float4 w67 = *(const float4*)(w8 + 6);
    float wr[8], wi[8];
    wr[1]=w01.z; wi[1]=w01.w; wr[2]=w23.x; wi[2]=w23.y; wr[3]=w23.z; wi[3]=w23.w;
    wr[4]=w45.x; wi[4]=w45.y; wr[5]=w45.z; wi[5]=w45.w; wr[6]=w67.x; wi[6]=w67.y; wr[7]=w67.z; wi[7]=w67.w;
#pragma unroll
    for (int j = 1; j < 8; ++j) {
        float a = yr[j], b = yi[j];
        yr[j] = fmaf(a, wr[j],  b * wi[j]);
        yi[j] = fmaf(b, wr[j], -a * wi[j]);
    }
}

// radix-8 DIF fwd stage on float2 LDS; PD2 hoisted: PD2(i1+j*ST) = PD2(i1) + j*(ST+ST/8)
template<int M, int TOFF>
__device__ __forceinline__ void s8f(float2* Z, int t, const float2* __restrict__ T) {
    constexpr int ST = M / 8;
    constexpr int STRIDE = (ST >= 16) ? (ST + ST / 8) : ST;
    const int k = t & (ST - 1);
    const int i1 = ((t & ~(ST - 1)) << 3) | k;
    const int b0 = PD2(i1);
    float xr[8], xi[8];
#pragma unroll
    for (int j = 0; j < 8; ++j) { float2 z = Z[b0 + j * STRIDE]; xr[j] = z.x; xi[j] = z.y; }
    float yr[8], yi[8];
    dft8<-1>(xr, xi, yr, yi);
    twmul_fwd(T + TOFF + k * 8, yr, yi);
#pragma unroll
    for (int j = 0; j < 8; ++j) Z[b0 + j * STRIDE] = make_float2(yr[j], yi[j]);
}

// radix-8 DIT inv stage on float2 LDS
template<int M, int TOFF>
__device__ __forceinline__ void s8i(float2* Z, int t, const float2* __restrict__ T) {
    constexpr int ST = M / 8;
    constexpr int STRIDE = (ST >= 16) ? (ST + ST / 8) : ST;
    const int k = t & (ST - 1);
    const int i1 = ((t & ~(ST - 1)) << 3) | k;
    const int b0 = PD2(i1);
    float xr[8], xi[8];
#pragma unroll
    for (int j = 0; j < 8; ++j) { float2 z = Z[b0 + j * STRIDE]; xr[j] = z.x; xi[j] = z.y; }
    twmul_inv(T + TOFF + k * 8, xr, xi);
    float yr[8], yi[8];
    dft8<1>(xr, xi, yr, yi);
#pragma unroll
    for (int j = 0; j < 8; ++j) Z[b0 + j * STRIDE] = make_float2(yr[j], yi[j]);
}

// untangle pair (k, 8192-k), multiply by H, retangle.  (c,s) = e^{-2pi i k/16384}
__device__ __forceinline__ void umr(float2 z, float2 z2, float c, float s,
                                    float2 Hk, float2 Hm, float2& spk, float2& spm)
{
    float xer = 0.5f*(z.x + z2.x), xei = 0.5f*(z.y - z2.y);
    float xor_ = 0.5f*(z.y + z2.y), xoi = 0.5f*(z2.x - z.x);
    float pr = xor_*c - xoi*s, pi = xor_*s + xoi*c;
    float xkr = xer + pr, xki = xei + pi;
    float xmr = xer - pr, xmi = pi - xei;
    float ykr = xkr*Hk.x - xki*Hk.y, yki = xkr*Hk.y + xki*Hk.x;
    float ymr = xmr*Hm.x - xmi*Hm.y, ymi = xmr*Hm.y + xmi*Hm.x;
    float yer = 0.5f*(ykr + ymr), yei = 0.5f*(yki - ymi);
    float dmr = 0.5f*(ykr - ymr), dmi = 0.5f*(yki + ymi);
    float yor = dmr*c + dmi*s, yoi = dmi*c - dmr*s;
    spk = make_float2(yer - yoi, yei + yor);
    spm = make_float2(yer + yoi, yor - yei);
}

// untangle only (for filter spectrum)
__device__ __forceinline__ void unt2(float2 z, float2 z2, float c, float s,
                                     float2& Xk, float2& Xm)
{
    float xer = 0.5f*(z.x + z2.x), xei = 0.5f*(z.y - z2.y);
    float xor_ = 0.5f*(z.y + z2.y), xoi = 0.5f*(z2.x - z.x);
    float pr = xor_*c - xoi*s, pi = xor_*s + xoi*c;
    Xk = make_float2(xer + pr, xei + pi);
    Xm = make_float2(xer - pr, pi - xei);
}

// storage-order orbit indexing: thread slot g -> storage p (chosen rep) and partner u.
// chosen p pieces: [1,3],[8,35],[64,287],[512,2303]; partner u = C - p piecewise.
__device__ __forceinline__ void orbit_pu(int g, int& p, int& u) {
    int off = (g < 4) ? 0 : (g < 32) ? 4 : (g < 256) ? 32 : 256;
    int C   = (g < 4) ? 8 : (g < 32) ? 71 : (g < 256) ? 575 : 4607;
    p = g + off;
    u = C - p;
}

// orbit conv in storage order: pa/pb lane-contiguous -> conflict-free b128 LDS,
// HFp pair-layout -> coalesced float4 H loads, twiddle from OT[p].
__device__ __forceinline__ void orbit_conv2(float2* Z, const float2* __restrict__ HFp,
                                            const float2* __restrict__ T, int g)
{
    int p, u; orbit_pu(g, p, u);
    const int pa = 2 * p + ((p >> 3) << 1);   // PD2(2p)
    const int pb = 2 * u + ((u >> 3) << 1);   // PD2(2u)
    float4 Af = *(const float4*)&Z[pa];
    float4 Bf = *(const float4*)&Z[pb];
    float2 Sq  = make_float2(Af.x + Af.z, Af.y + Af.w);   // S[q],       q = P2h(p)
    float2 Sq4 = make_float2(Af.x - Af.z, Af.y - Af.w);   // S[q+4096]
    float2 Sk2 = make_float2(Bf.x + Bf.z, Bf.y + Bf.w);   // S[4096-q]
    float2 Smq = make_float2(Bf.x - Bf.z, Bf.y - Bf.w);   // S[8192-q]
    float2 cs = T[OTB + p];                               // e^{-2pi i q/16384}
    float4 Hq = *(const float4*)&HFp[2 * p];              // H[q], H[8192-q]
    float4 Hu = *(const float4*)&HFp[2 * u];              // H[4096-q], H[4096+q]
    float2 sp_q, sp_mq, sp_k2, sp_mk2;
    umr(Sq,  Smq,  cs.x,  cs.y, make_float2(Hq.x, Hq.y), make_float2(Hq.z, Hq.w), sp_q,  sp_mq);
    umr(Sk2, Sq4, -cs.y, -cs.x, make_float2(Hu.x, Hu.y), make_float2(Hu.z, Hu.w), sp_k2, sp_mk2);
    float4 oa, ob;
    oa.x = sp_q.x + sp_mk2.x; oa.y = sp_q.y + sp_mk2.y;
    oa.z = sp_q.x - sp_mk2.x; oa.w = sp_q.y - sp_mk2.y;
    ob.x = sp_k2.x + sp_mq.x; ob.y = sp_k2.y + sp_mq.y;
    ob.z = sp_k2.x - sp_mq.x; ob.w = sp_k2.y - sp_mq.y;
    *(float4*)&Z[pa] = oa;
    *(float4*)&Z[pb] = ob;
}

__device__ __forceinline__ void orbit_filter2(float2* Z, float2* __restrict__ out,
                                              const float2* __restrict__ T, int g)
{
    int p, u; orbit_pu(g, p, u);
    const int pa = 2 * p + ((p >> 3) << 1);
    const int pb = 2 * u + ((u >> 3) << 1);
    float4 Af = *(const float4*)&Z[pa];
    float4 Bf = *(const float4*)&Z[pb];
    float2 Sq  = make_float2(Af.x + Af.z, Af.y + Af.w);
    float2 Sq4 = make_float2(Af.x - Af.z, Af.y - Af.w);
    float2 Sk2 = make_float2(Bf.x + Bf.z, Bf.y + Bf.w);
    float2 Smq = make_float2(Bf.x - Bf.z, Bf.y - Bf.w);
    float2 cs = T[OTB + p];
    float2 Xa, Xb, Xc, Xd;
    unt2(Sq,  Smq,  cs.x,  cs.y, Xa, Xb);    // X[q], X[8192-q]
    unt2(Sk2, Sq4, -cs.y, -cs.x, Xc, Xd);    // X[4096-q], X[4096+q]
    *(float4*)&out[2 * p] = make_float4(Xa.x, Xa.y, Xb.x, Xb.y);
    *(float4*)&out[2 * u] = make_float4(Xc.x, Xc.y, Xd.x, Xd.y);
}

// ---------------------------------------------------------------------------
// twiddle-table init (writes into d_out scratch; gemm_out_k overwrites later)
// ---------------------------------------------------------------------------
__global__ __launch_bounds__(256) void tw_init(float2* __restrict__ T)
{
    const int id = blockIdx.x * 256 + threadIdx.x;
    if (id < 1170) {
        int M, k, base;
        if (id < 1024)      { M = 8192; k = id;        base = TW0 + k * 8; }
        else if (id < 1152) { M = 1024; k = id - 1024; base = TW1 + k * 8; }
        else if (id < 1168) { M = 128;  k = id - 1152; base = TW2 + k * 8; }
        else                { M = 16;   k = id - 1168; base = TW3 + k * 8; }
#pragma unroll
        for (int j = 0; j < 8; ++j) {
            float ang = -6.283185307179586f * (float)(j * k) / (float)M;
            float s, c;
            __sincosf(ang, &s, &c);
            T[base + j] = make_float2(c, s);
        }
    } else if (id < 1170 + 2304) {
        int p = id - 1170;
        int q = P2h(p);
        float s, c;
        __sincosf(-ANGN * (float)q, &s, &c);
        T[OTB + p] = make_float2(c, s);
    }
}

// ---------------------------------------------------------------------------
// GEMM A: proj[n, m] = sum_k in_W[n,k] * x[m,k] + in_b[n]
// XCD-affine swizzle; output proj[seg][b*256+c][l] bf16
// ---------------------------------------------------------------------------
__global__ __launch_bounds__(256) void gemm_proj(
    const float* __restrict__ x, const float* __restrict__ inW, const float* __restrict__ inb,
    bf16* __restrict__ proj)
{
    __shared__ __align__(16) short sW[64 * 64];
    __shared__ __align__(16) short sX[256 * 64];
    const int tid = threadIdx.x;
    const int wave = tid >> 6, lane = tid & 63, quad = lane >> 4, l16 = lane & 15;
    const int id = blockIdx.x;
    const int xcd = id & 7, chunk = id >> 3;
    const int bn = (chunk % 12) * 64;
    const int bm = ((chunk / 12) * 8 + xcd) * 256;

    floatx4 acc[4][4];
#pragma unroll
    for (int i = 0; i < 4; ++i)
#pragma unroll
        for (int j = 0; j < 4; ++j) acc[i][j] = (floatx4){0.f, 0.f, 0.f, 0.f};

    const int r0 = tid >> 3, c0 = (tid & 7) * 8;
    for (int s = 0; s < 4; ++s) {
        const int koff = s * 64;
        short8 wreg[2], xreg[8];
#pragma unroll
        for (int j = 0; j < 2; ++j) {
            const float* p = inW + (size_t)(bn + j * 32 + r0) * 256 + koff + c0;
            wreg[j] = pack8(*(const float4*)p, *(const float4*)(p + 4));
        }
#pragma unroll
        for (int j = 0; j < 8; ++j) {
            const float* p = x + (size_t)(bm + j * 32 + r0) * 256 + koff + c0;
            xreg[j] = pack8(*(const float4*)p, *(const float4*)(p + 4));
        }
        __syncthreads();
#pragma unroll
        for (int j = 0; j < 2; ++j)
            *(short8*)(&sW[SWZ(j * 32 + r0, c0)]) = wreg[j];
#pragma unroll
        for (int j = 0; j < 8; ++j)
            *(short8*)(&sX[SWZ(j * 32 + r0, c0)]) = xreg[j];
        __syncthreads();
#pragma unroll
        for (int kk = 0; kk < 64; kk += 32) {
            const int ko = kk + quad * 8;
            short8 wf[4], xf[4];
#pragma unroll
            for (int ts = 0; ts < 4; ++ts)
                wf[ts] = *(const short8*)(&sW[SWZ(ts * 16 + l16, ko)]);
#pragma unroll
            for (int tb = 0; tb < 4; ++tb)
                xf[tb] = *(const short8*)(&sX[SWZ(wave * 64 + tb * 16 + l16, ko)]);
#pragma unroll
            for (int ts = 0; ts < 4; ++ts)
#pragma unroll
                for (int tb = 0; tb < 4; ++tb)
                    acc[ts][tb] = __builtin_amdgcn_mfma_f32_16x16x32_bf16(
                        wf[ts], xf[tb], acc[ts][tb], 0, 0, 0);
        }
    }
    const int seg = bn >> 8;
#pragma unroll
    for (int ts = 0; ts < 4; ++ts) {
#pragma unroll
        for (int r = 0; r < 4; ++r) {
            const int nglob = bn + ts * 16 + quad * 4 + r;
            const float bias = inb[nglob];
            const int c = nglob & 255;
#pragma unroll
            for (int tb = 0; tb < 4; ++tb) {
                const int m = bm + wave * 64 + tb * 16 + l16;
                const int bb = m >> 13, l = m & 8191;
                const size_t idx = ((size_t)(seg * 2048 + bb * 256 + c)) * 8192 + l;
                proj[idx] = f2b(acc[ts][tb][r] + bias);
            }
        }
    }
}

// ---------------------------------------------------------------------------
// GEMM F: out[m, n] = sum_k gated[m,k] * out_W[n,k] + out_b[n]
// ---------------------------------------------------------------------------
__global__ __launch_bounds__(256) void gemm_out_k(
    const bf16* __restrict__ gated, const float* __restrict__ outW, const float* __restrict__ outb,
    float* __restrict__ out)
{
    __shared__ __align__(16) short sW[64 * 64];
    __shared__ __align__(16) short sA[256 * 64];
    const int tid = threadIdx.x;
    const int wave = tid >> 6, lane = tid & 63, quad = lane >> 4, l16 = lane & 15;
    const int id = blockIdx.x;
    const int xcd = id & 7, chunk = id >> 3;
    const int bn = (chunk & 3) * 64;
    const int bm = ((chunk >> 2) * 8 + xcd) * 256;

    floatx4 acc[4][4];
#pragma unroll
    for (int i = 0; i < 4; ++i)
#pragma unroll
        for (int j = 0; j < 4; ++j) acc[i][j] = (floatx4){0.f, 0.f, 0.f, 0.f};

    const int r0 = tid >> 3, c0 = (tid & 7) * 8;
    for (int s = 0; s < 4; ++s) {
        const int koff = s * 64;
        short8 wreg[2];
        uint4 areg[8];
#pragma unroll
        for (int j = 0; j < 2; ++j) {
            const float* p = outW + (size_t)(bn + j * 32 + r0) * 256 + koff + c0;
            wreg[j] = pack8(*(const float4*)p, *(const float4*)(p + 4));
        }
#pragma unroll
        for (int j = 0; j < 8; ++j)
            areg[j] = *(const uint4*)(gated + (size_t)(bm + j * 32 + r0) * 256 + koff + c0);
        __syncthreads();
#pragma unroll
        for (int j = 0; j < 2; ++j)
            *(short8*)(&sW[SWZ(j * 32 + r0, c0)]) = wreg[j];
#pragma unroll
        for (int j = 0; j < 8; ++j)
            *(uint4*)(&sA[SWZ(j * 32 + r0, c0)]) = areg[j];
        __syncthreads();
#pragma unroll
        for (int kk = 0; kk < 64; kk += 32) {
            const int ko = kk + quad * 8;
            short8 bfr[4], af[4];
#pragma unroll
            for (int ts = 0; ts < 4; ++ts)
                bfr[ts] = *(const short8*)(&sW[SWZ(ts * 16 + l16, ko)]);
#pragma unroll
            for (int tb = 0; tb < 4; ++tb)
                af[tb] = *(const short8*)(&sA[SWZ(wave * 64 + tb * 16 + l16, ko)]);
#pragma unroll
            for (int tb = 0; tb < 4; ++tb)
#pragma unroll
                for (int ts = 0; ts < 4; ++ts)
                    acc[tb][ts] = __builtin_amdgcn_mfma_f32_16x16x32_bf16(
                        af[tb], bfr[ts], acc[tb][ts], 0, 0, 0);
        }
    }
#pragma unroll
    for (int tb = 0; tb < 4; ++tb) {
#pragma unroll
        for (int r = 0; r < 4; ++r) {
            const int m = bm + wave * 64 + tb * 16 + quad * 4 + r;
#pragma unroll
            for (int ts = 0; ts < 4; ++ts) {
                const int n = bn + ts * 16 + l16;
                out[(size_t)m * 256 + n] = acc[tb][ts][r] + outb[n];
            }
        }
    }
}

// ---------------------------------------------------------------------------
// h[d, l] = silu(t_l*W1 + b1) @ W2[d,:] + b2[d]   (all fp32)
// ---------------------------------------------------------------------------
__global__ __launch_bounds__(256) void build_h(
    const float* __restrict__ tpos, const float* __restrict__ W1, const float* __restrict__ b1,
    const float* __restrict__ W2, const float* __restrict__ b2, float* __restrict__ h)
{
    __shared__ float s[32][64];
    __shared__ float tr[256 * 32];
    const int tid = threadIdx.x;
    const int l0 = blockIdx.x * 32;
#pragma unroll
    for (int p = 0; p < 8; ++p) {
        int idx = tid + p * 256;
        int li = idx >> 6, j = idx & 63;
        float tv = tpos[l0 + li];
        float z = tv * W1[j] + b1[j];
        s[li][j] = z / (1.f + __expf(-z));
    }
    __syncthreads();
    const int d = tid;
    float acc[32];
    float bb = b2[d];
#pragma unroll
    for (int li = 0; li < 32; ++li) acc[li] = bb;
    for (int j = 0; j < 64; ++j) {
        float w = W2[d * 64 + j];
#pragma unroll
        for (int li = 0; li < 32; ++li) acc[li] += w * s[li][j];
    }
#pragma unroll
    for (int li = 0; li < 32; ++li) tr[d * 32 + li] = acc[li];
    __syncthreads();
#pragma unroll
    for (int p = 0; p < 8; ++p) {
        int idx = tid + p * 256;
        int row = idx >> 3, c = (idx & 7) * 4;
        *(float4*)(h + (size_t)row * 8192 + l0 + c) = *(const float4*)(&tr[row * 32 + c]);
    }
}

// ---------------------------------------------------------------------------
// hf (pair layout): HFp[2p]=X[P2h(p)], HFp[2p+1]=X[8192-P2h(p)]; HFp[8192]=X[4096]
// ---------------------------------------------------------------------------
__global__ __launch_bounds__(1024, 8) void fft_filter(
    const float* __restrict__ h, float2* __restrict__ hf, const float2* __restrict__ T)
{
    __shared__ __align__(16) float2 Z[9216];
    const int d = blockIdx.x;
    const int t = threadIdx.x;
    const float2* hrow = (const float2*)(h + (size_t)d * L_SZ);
    // fused first stage (M=8192): inputs j>=4 are zero
    {
        const int b0 = PD2(t);
        float xr[8], xi[8];
#pragma unroll
        for (int j = 0; j < 4; ++j) { float2 z = hrow[t + (j << 10)]; xr[j] = z.x; xi[j] = z.y; }
#pragma unroll
        for (int j = 4; j < 8; ++j) { xr[j] = 0.f; xi[j] = 0.f; }
        float yr[8], yi[8];
        dft8<-1>(xr, xi, yr, yi);
        twmul_fwd(T + TW0 + t * 8, yr, yi);
#pragma unroll
        for (int j = 0; j < 8; ++j) Z[b0 + j * 1152] = make_float2(yr[j], yi[j]);
    }
    __syncthreads();
    s8f<1024, TW1>(Z, t, T); __syncthreads();
    s8f<128,  TW2>(Z, t, T); __syncthreads();
    s8f<16,   TW3>(Z, t, T); __syncthreads();
    float2* outp = hf + (size_t)d * HFS;
    if (t == 0) {
        float4 Af = *(const float4*)&Z[0];
        float2 S0 = make_float2(Af.x + Af.z, Af.y + Af.w);
        float2 S4 = make_float2(Af.x - Af.z, Af.y - Af.w);
        outp[0]    = make_float2(S0.x + S0.y, 0.f);   // X[0]
        outp[1]    = make_float2(S0.x - S0.y, 0.f);   // X[8192]
        outp[8192] = make_float2(S4.x, -S4.y);        // X[4096]
        float4 Bf = *(const float4*)&Z[8];            // p=4 degenerate orbit (q=2048)
        float2 S2k = make_float2(Bf.x + Bf.z, Bf.y + Bf.w);
        float2 S6k = make_float2(Bf.x - Bf.z, Bf.y - Bf.w);
        const float R2 = 0.70710678118654752f;
        float2 Xa, Xb;
        unt2(S2k, S6k, R2, -R2, Xa, Xb);
        outp[8] = Xa; outp[9] = Xb;                   // X[2048], X[6144]
    } else {
        orbit_filter2(Z, outp, T, t);
    }
    orbit_filter2(Z, outp, T, t + 1024);
}

// ---------------------------------------------------------------------------
// per (b,d): y = irfft(rfft(v)*hf[d])[:L]; gate with both dwconvs; write gatedT
// ---------------------------------------------------------------------------
__global__ __launch_bounds__(1024, 8) void fft_conv(
    const bf16* __restrict__ proj, const float2* __restrict__ hf, const float2* __restrict__ T,
    const float* __restrict__ cw0, const float* __restrict__ cb0,
    const float* __restrict__ cw1, const float* __restrict__ cb1,
    bf16* __restrict__ gatedT)
{
    __shared__ __align__(16) float2 Z[9216];
    const int bid = blockIdx.x;
    // XCD-affine: the 8 batch-blocks sharing hf[d] land on the same XCD (bid%8 fixed)
    const int d = ((bid >> 6) << 3) | (bid & 7);
    const int b = (bid >> 3) & 7;
    const int t = threadIdx.x;
    const size_t rowoff = ((size_t)(b * 256 + d)) * L_SZ;
    // fused first stage: bf16 v row -> complex packed, upper half zero
    {
        const unsigned int* vrow = (const unsigned int*)(proj + rowoff);
        const int b0 = PD2(t);
        float xr[8], xi[8];
#pragma unroll
        for (int j = 0; j < 4; ++j) {
            unsigned int u = vrow[t + (j << 10)];
            xr[j] = lo2f(u); xi[j] = hi2f(u);
        }
#pragma unroll
        for (int j = 4; j < 8; ++j) { xr[j] = 0.f; xi[j] = 0.f; }
        float yr[8], yi[8];
        dft8<-1>(xr, xi, yr, yi);
        twmul_fwd(T + TW0 + t * 8, yr, yi);
#pragma unroll
        for (int j = 0; j < 8; ++j) Z[b0 + j * 1152] = make_float2(yr[j], yi[j]);
    }
    __syncthreads();
    s8f<1024, TW1>(Z, t, T); __syncthreads();
    s8f<128,  TW2>(Z, t, T); __syncthreads();
    s8f<16,   TW3>(Z, t, T); __syncthreads();
    const float2* H = hf + (size_t)d * HFS;
    if (t == 0) {
        // orbit {0, 4096}
        float4 Af = *(const float4*)&Z[0];
        float2 S0 = make_float2(Af.x + Af.z, Af.y + Af.w);
        float2 S4 = make_float2(Af.x - Af.z, Af.y - Af.w);
        float x0 = S0.x + S0.y, xm = S0.x - S0.y;
        float2 H0 = H[0], Hm = H[1], H4 = H[8192];
        float y0r = x0 * H0.x, y0i = x0 * H0.y;
        float ymr = xm * Hm.x, ymi = xm * Hm.y;
        float yer = 0.5f*(y0r + ymr), yei = 0.5f*(y0i + ymi);
        float yor = 0.5f*(y0r - ymr), yoi = 0.5f*(y0i - ymi);
        float2 spdc = make_float2(yer - yoi, yei + yor);
        float y4r = S4.x * H4.x + S4.y * H4.y;
        float y4i = S4.x * H4.y - S4.y * H4.x;
        float2 sp4 = make_float2(y4r, -y4i);
        Z[0] = make_float2(spdc.x + sp4.x, spdc.y + sp4.y);
        Z[1] = make_float2(spdc.x - sp4.x, spdc.y - sp4.y);
        // p=4 degenerate orbit {2048, 6144}
        float4 Bf = *(const float4*)&Z[8];
        float2 S2k = make_float2(Bf.x + Bf.z, Bf.y + Bf.w);
        float2 S6k = make_float2(Bf.x - Bf.z, Bf.y - Bf.w);
        const float R2 = 0.70710678118654752f;
        float2 spa, spb;
        umr(S2k, S6k, R2, -R2, H[8], H[9], spa, spb);
        Z[8] = make_float2(spa.x + spb.x, spa.y + spb.y);
        Z[9] = make_float2(spa.x - spb.x, spa.y - spb.y);
    } else {
        orbit_conv2(Z, H, T, t);
    }
    orbit_conv2(Z, H, T, t + 1024);
    __syncthreads();
    s8i<16,   TW3>(Z, t, T); __syncthreads();
    s8i<128,  TW2>(Z, t, T); __syncthreads();
    s8i<1024, TW1>(Z, t, T); __syncthreads();
    // fused final inverse stage (M=8192) + gating epilogue
    const int b0 = PD2(t);
    float xr[8], xi[8];
#pragma unroll
    for (int j = 0; j < 8; ++j) { float2 z = Z[b0 + j * 1152]; xr[j] = z.x; xi[j] = z.y; }
    twmul_inv(T + TW0 + t * 8, xr, xi);
    float yr[8], yi[8];
    dft8<1>(xr, xi, yr, yi);
    const float sc = 1.0f / 8192.0f;
    const float w00 = cw0[d * 3], w01 = cw0[d * 3 + 1], w02 = cw0[d * 3 + 2], bi0 = cb0[d];
    const float w10 = cw1[d * 3], w11 = cw1[d * 3 + 1], w12 = cw1[d * 3 + 2], bi1 = cb1[d];
    const unsigned int* R0 = (const unsigned int*)(proj + (size_t)2048 * L_SZ + rowoff);
    const unsigned int* R1 = (const unsigned int*)(proj + (size_t)4096 * L_SZ + rowoff);
    unsigned int* gout = (unsigned int*)gatedT + ((size_t)d * 32768 + b * 4096);
#pragma unroll
    for (int j = 0; j < 4; ++j) {
        const int n = t + (j << 10);
        const float v0 = yr[j] * sc;
        const float v1 = yi[j] * sc;
        unsigned int m0u = (n > 0) ? R0[n - 1] : 0u;
        unsigned int c0u = R0[n];
        unsigned int p0u = (n < 4095) ? R0[n + 1] : 0u;
        unsigned int m1u = (n > 0) ? R1[n - 1] : 0u;
        unsigned int c1u = R1[n];
        unsigned int p1u = (n < 4095) ? R1[n + 1] : 0u;
        float g00 = w00 * hi2f(m0u) + w01 * lo2f(c0u) + w02 * hi2f(c0u) + bi0;
        float g01 = w00 * lo2f(c0u) + w01 * hi2f(c0u) + w02 * lo2f(p0u) + bi0;
        float g10 = w10 * hi2f(m1u) + w11 * lo2f(c1u) + w12 * hi2f(c1u) + bi1;
        float g11 = w10 * lo2f(c1u) + w11 * hi2f(c1u) + w12 * lo2f(p1u) + bi1;
        unsigned int o = (unsigned int)f2bu(v0 * g00 * g10)
                       | ((unsigned int)f2bu(v1 * g01 * g11) << 16);
        gout[n] = o;
    }
}

// ---------------------------------------------------------------------------
// gatedT[256][65536] -> gated[65536][256]  (bf16 transpose, 64x64 tiles)
// ---------------------------------------------------------------------------
__global__ __launch_bounds__(256) void transpose_k(
    const ushort* __restrict__ gatedT, ushort* __restrict__ gated)
{
    __shared__ ushort T2[64 * 66];
    const int tid = threadIdx.x;
    const int m0 = blockIdx.x * 64, d0 = blockIdx.y * 64;
    const int rr = tid >> 3, co = (tid & 7) * 8;
#pragma unroll
    for (int it = 0; it < 2; ++it) {
        const int dr = rr + 32 * it;
        const uint4 val = *(const uint4*)(gatedT + (size_t)(d0 + dr) * 65536 + m0 + co);
        const ushort* vs = (const ushort*)&val;
#pragma unroll
        for (int i = 0; i < 8; ++i)
            T2[(co + i) * 66 + dr] = vs[i];
    }
    __syncthreads();
#pragma unroll
    for (int it = 0; it < 2; ++it) {
        const int mr = rr + 32 * it;
        uint w0 = *(const uint*)(T2 + mr * 66 + co);
        uint w1 = *(const uint*)(T2 + mr * 66 + co + 2);
        uint w2 = *(const uint*)(T2 + mr * 66 + co + 4);
        uint w3 = *(const uint*)(T2 + mr * 66 + co + 6);
        uint4 ov; ov.x = w0; ov.y = w1; ov.z = w2; ov.w = w3;
        *(uint4*)(gated + (size_t)(m0 + mr) * 256 + d0 + co) = ov;
    }
}

// ---------------------------------------------------------------------------
extern "C" void kernel_launch(void* const* d_in, const int* in_sizes, int n_in,
                              void* d_out, int out_size, void* d_ws, size_t ws_size,
                              hipStream_t stream)
{
    const float* x    = (const float*)d_in[0];
    const float* inW  = (const float*)d_in[1];
    const float* inb  = (const float*)d_in[2];
    const float* c0W  = (const float*)d_in[3];
    const float* c0b  = (const float*)d_in[4];
    const float* c1W  = (const float*)d_in[5];
    const float* c1b  = (const float*)d_in[6];
    const float* mW1  = (const float*)d_in[7];
    const float* mb1  = (const float*)d_in[8];
    const float* mW2  = (const float*)d_in[9];
    const float* mb2  = (const float*)d_in[10];
    const float* oW   = (const float*)d_in[11];
    const float* ob   = (const float*)d_in[12];
    const float* tpos = (const float*)d_in[13];
    float* out = (float*)d_out;

    char* ws = (char*)d_ws;
    // ws: only persistent intermediates (168 MB, below previously-verified 193 MB)
    bf16*   proj   = (bf16*)(ws);                    // 96 MB [3][2048][8192]: v, raw0, raw1
    bf16*   gatedT = (bf16*)(ws + 100663296);        // 32 MB [256][65536]
    bf16*   gated  = (bf16*)(ws + 134217728);        // 32 MB [65536][256]
    float*  h      = (float*)(ws + 167772160);       // 8 MB [256][8192]
    // twiddle tables + hf live in d_out scratch: read only before transpose/gemm_out,
    // then fully overwritten by gemm_out_k (stream-ordered, race-free).
    float2* T  = (float2*)d_out;                                   // ~93 KB tables
    float2* hf = (float2*)((char*)d_out + HF_BYTE_OFF);            // 16.78 MB [256][HFS]

    tw_init<<<14, 256, 0, stream>>>(T);
    build_h<<<256, 256, 0, stream>>>(tpos, mW1, mb1, mW2, mb2, h);
    fft_filter<<<256, 1024, 0, stream>>>(h, hf, T);
    gemm_proj<<<3072, 256, 0, stream>>>(x, inW, inb, proj);
    fft_conv<<<2048, 1024, 0, stream>>>(proj, hf, T, c0W, c0b, c1W, c1b, gatedT);
    transpose_k<<<dim3(1024, 4), 256, 0, stream>>>((const ushort*)gatedT, (ushort*)gated);
    gemm_out_k<<<1024, 256, 0, stream>>>(gated, oW, ob, out);
}

// Round 3
// 319.096 us; speedup vs baseline: 1.2888x; 1.2089x over previous
//
#include <hip/hip_runtime.h>
#include <hip/hip_bf16.h>

typedef __hip_bfloat16 bf16;
typedef __attribute__((ext_vector_type(8))) short short8;
typedef __attribute__((ext_vector_type(4))) float floatx4;

#define L_SZ 8192
#define HFS 8194        // hf row stride in float2 (pair-layout, 16B-aligned rows)
#define PD2(i) ((i) + (((i) >> 4) << 1))   // float2 LDS pad: +2 per 16 (keeps pairs 16B-aligned)
#define SWZ(row, col) ((row) * 64 + ((col) ^ (((row) & 7) * 8)))   // GEMM LDS swizzle
#define ANGN 3.83495197e-4f    // 2*pi/16384

// twiddle table layout (float2 units) — lives in d_out scratch (overwritten by gemm_out_k at end)
#define TW0 0        // M=8192, k=0..1023, 8 powers each
#define TW1 8192     // M=1024, k=0..127
#define TW2 9216     // M=128,  k=0..15
#define TW3 9344     // M=16,   k=0..1
#define OTB 9360     // orbit untangle twiddles, indexed by storage p, 2304 entries
#define HF_BYTE_OFF 131072     // hf region offset within d_out
#define XB_BYTE_OFF 25165824   // xb (bf16 x) region offset within d_out (32 MB, ends at 56 MB < 64 MB)

__device__ __forceinline__ float b2f(bf16 x) { return __bfloat162float(x); }
__device__ __forceinline__ bf16 f2b(float x) { return __float2bfloat16(x); }
__device__ __forceinline__ float lo2f(unsigned int u) { return __uint_as_float(u << 16); }
__device__ __forceinline__ float hi2f(unsigned int u) { return __uint_as_float(u & 0xffff0000u); }
__device__ __forceinline__ unsigned short f2bu(float x) {
    bf16 b = __float2bfloat16(x);
    return *reinterpret_cast<unsigned short*>(&b);
}
__device__ __forceinline__ short f2bs(float x) {
    bf16 b = __float2bfloat16(x);
    return *reinterpret_cast<short*>(&b);
}
__device__ __forceinline__ short8 pack8(float4 a, float4 b) {
    short8 r;
    r[0] = f2bs(a.x); r[1] = f2bs(a.y); r[2] = f2bs(a.z); r[3] = f2bs(a.w);
    r[4] = f2bs(b.x); r[5] = f2bs(b.y); r[6] = f2bs(b.z); r[7] = f2bs(b.w);
    return r;
}

// async global->LDS DMA, 16B per lane; LDS dest is wave-uniform base (+lane*16 by HW)
__device__ __forceinline__ void glds16(const void* g, void* l) {
    __builtin_amdgcn_global_load_lds(
        (const __attribute__((address_space(1))) unsigned int*)g,
        (__attribute__((address_space(3))) unsigned int*)l, 16, 0, 0);
}

// half-perm: storage position pair-base of frequency q (q<4096) after DIF [8,8,8,8,(2)]
__device__ __forceinline__ int P2h(int k) {
    return ((k & 7) << 9) | (((k >> 3) & 7) << 6) | (((k >> 6) & 7) << 3) | ((k >> 9) & 7);
}

// ---------------------------------------------------------------------------
// 8-point DFT, SF=-1 forward, SF=+1 inverse
// ---------------------------------------------------------------------------
template<int SF>
__device__ __forceinline__ void dft8(const float xr[8], const float xi[8],
                                     float yr[8], float yi[8]) {
    constexpr float sgn = (SF < 0) ? -1.f : 1.f;
    const float S2 = 0.70710678118654752f;
    float t0r=xr[0]+xr[4], t0i=xi[0]+xi[4];
    float t1r=xr[0]-xr[4], t1i=xi[0]-xi[4];
    float t2r=xr[2]+xr[6], t2i=xi[2]+xi[6];
    float t3r=xr[2]-xr[6], t3i=xi[2]-xi[6];
    float u0r=xr[1]+xr[5], u0i=xi[1]+xi[5];
    float u1r=xr[1]-xr[5], u1i=xi[1]-xi[5];
    float u2r=xr[3]+xr[7], u2i=xi[3]+xi[7];
    float u3r=xr[3]-xr[7], u3i=xi[3]-xi[7];
    float m3r = -sgn*t3i, m3i = sgn*t3r;
    float n3r = -sgn*u3i, n3i = sgn*u3r;
    float E0r=t0r+t2r, E0i=t0i+t2i, E2r=t0r-t2r, E2i=t0i-t2i;
    float E1r=t1r+m3r, E1i=t1i+m3i, E3r=t1r-m3r, E3i=t1i-m3i;
    float O0r=u0r+u2r, O0i=u0i+u2i, O2r=u0r-u2r, O2i=u0i-u2i;
    float O1r=u1r+n3r, O1i=u1i+n3i, O3r=u1r-n3r, O3i=u1i-n3i;
    float a1r = S2*(O1r - sgn*O1i),  a1i = S2*(O1i + sgn*O1r);
    float a2r = -sgn*O2i,            a2i = sgn*O2r;
    float a3r = S2*(-O3r - sgn*O3i), a3i = S2*(sgn*O3r - O3i);
    yr[0]=E0r+O0r; yi[0]=E0i+O0i; yr[4]=E0r-O0r; yi[4]=E0i-O0i;
    yr[1]=E1r+a1r; yi[1]=E1i+a1i; yr[5]=E1r-a1r; yi[5]=E1i-a1i;
    yr[2]=E2r+a2r; yi[2]=E2i+a2i; yr[6]=E2r-a2r; yi[6]=E2i-a2i;
    yr[3]=E3r+a3r; yi[3]=E3i+a3i; yr[7]=E3r-a3r; yi[7]=E3i-a3i;
}

// apply table twiddles w^j (forward table holds e^{-i*j*theta}) to y[1..7]
__device__ __forceinline__ void twmul_fwd(const float2* __restrict__ w8, float yr[8], float yi[8]) {
    float4 w01 = *(const float4*)(w8);
    float4 w23 = *(const float4*)(w8 + 2);
    float4 w45 = *(const float4*)(w8 + 4);
    float4 w67 = *(const float4*)(w8 + 6);
    float wr[8], wi[8];
    wr[1]=w01.z; wi[1]=w01.w; wr[2]=w23.x; wi[2]=w23.y; wr[3]=w23.z; wi[3]=w23.w;
    wr[4]=w45.x; wi[4]=w45.y; wr[5]=w45.z; wi[5]=w45.w; wr[6]=w67.x; wi[6]=w67.y; wr[7]=w67.z; wi[7]=w67.w;
#pragma unroll
    for (int j = 1; j < 8; ++j) {
        float a = yr[j], b = yi[j];
        yr[j] = fmaf(a, wr[j], -b * wi[j]);
        yi[j] = fmaf(a, wi[j],  b * wr[j]);
    }
}
// conjugate (inverse) application of the same forward table
__device__ __forceinline__ void twmul_inv(const float2* __restrict__ w8, float yr[8], float yi[8]) {
    float4 w01 = *(const float4*)(w8);
    float4 w23 = *(const float4*)(w8 + 2);
    float4 w45 = *(const float4*)(w8 + 4);
    float4 w67 = *(const float4*)(w8 + 6);
    float wr[8], wi[8];
    wr[1]=w01.z; wi[1]=w01.w; wr[2]=w23.x; wi[2]=w23.y; wr[3]=w23.z; wi[3]=w23.w;
    wr[4]=w45.x; wi[4]=w45.y; wr[5]=w45.z; wi[5]=w45.w; wr[6]=w67.x; wi[6]=w67.y; wr[7]=w67.z; wi[7]=w67.w;
#pragma unroll
    for (int j = 1; j < 8; ++j) {
        float a = yr[j], b = yi[j];
        yr[j] = fmaf(a, wr[j],  b * wi[j]);
        yi[j] = fmaf(b, wr[j], -a * wi[j]);
    }
}

// radix-8 DIF fwd stage on float2 LDS; PD2 hoisted: PD2(i1+j*ST) = PD2(i1) + j*(ST+ST/8)
template<int M, int TOFF>
__device__ __forceinline__ void s8f(float2* Z, int t, const float2* __restrict__ T) {
    constexpr int ST = M / 8;
    constexpr int STRIDE = (ST >= 16) ? (ST + ST / 8) : ST;
    const int k = t & (ST - 1);
    const int i1 = ((t & ~(ST - 1)) << 3) | k;
    const int b0 = PD2(i1);
    float xr[8], xi[8];
#pragma unroll
    for (int j = 0; j < 8; ++j) { float2 z = Z[b0 + j * STRIDE]; xr[j] = z.x; xi[j] = z.y; }
    float yr[8], yi[8];
    dft8<-1>(xr, xi, yr, yi);
    twmul_fwd(T + TOFF + k * 8, yr, yi);
#pragma unroll
    for (int j = 0; j < 8; ++j) Z[b0 + j * STRIDE] = make_float2(yr[j], yi[j]);
}

// radix-8 DIT inv stage on float2 LDS
template<int M, int TOFF>
__device__ __forceinline__ void s8i(float2* Z, int t, const float2* __restrict__ T) {
    constexpr int ST = M / 8;
    constexpr int STRIDE = (ST >= 16) ? (ST + ST / 8) : ST;
    const int k = t & (ST - 1);
    const int i1 = ((t & ~(ST - 1)) << 3) | k;
    const int b0 = PD2(i1);
    float xr[8], xi[8];
#pragma unroll
    for (int j = 0; j < 8; ++j) { float2 z = Z[b0 + j * STRIDE]; xr[j] = z.x; xi[j] = z.y; }
    twmul_inv(T + TOFF + k * 8, xr, xi);
    float yr[8], yi[8];
    dft8<1>(xr, xi, yr, yi);
#pragma unroll
    for (int j = 0; j < 8; ++j) Z[b0 + j * STRIDE] = make_float2(yr[j], yi[j]);
}

// untangle pair (k, 8192-k), multiply by H, retangle.  (c,s) = e^{-2pi i k/16384}
__device__ __forceinline__ void umr(float2 z, float2 z2, float c, float s,
                                    float2 Hk, float2 Hm, float2& spk, float2& spm)
{
    float xer = 0.5f*(z.x + z2.x), xei = 0.5f*(z.y - z2.y);
    float xor_ = 0.5f*(z.y + z2.y), xoi = 0.5f*(z2.x - z.x);
    float pr = xor_*c - xoi*s, pi = xor_*s + xoi*c;
    float xkr = xer + pr, xki = xei + pi;
    float xmr = xer - pr, xmi = pi - xei;
    float ykr = xkr*Hk.x - xki*Hk.y, yki = xkr*Hk.y + xki*Hk.x;
    float ymr = xmr*Hm.x - xmi*Hm.y, ymi = xmr*Hm.y + xmi*Hm.x;
    float yer = 0.5f*(ykr + ymr), yei = 0.5f*(yki - ymi);
    float dmr = 0.5f*(ykr - ymr), dmi = 0.5f*(yki + ymi);
    float yor = dmr*c + dmi*s, yoi = dmi*c - dmr*s;
    spk = make_float2(yer - yoi, yei + yor);
    spm = make_float2(yer + yoi, yor - yei);
}

// untangle only (for filter spectrum)
__device__ __forceinline__ void unt2(float2 z, float2 z2, float c, float s,
                                     float2& Xk, float2& Xm)
{
    float xer = 0.5f*(z.x + z2.x), xei = 0.5f*(z.y - z2.y);
    float xor_ = 0.5f*(z.y + z2.y), xoi = 0.5f*(z2.x - z.x);
    float pr = xor_*c - xoi*s, pi = xor_*s + xoi*c;
    Xk = make_float2(xer + pr, xei + pi);
    Xm = make_float2(xer - pr, pi - xei);
}

// storage-order orbit indexing: thread slot g -> storage p (chosen rep) and partner u.
__device__ __forceinline__ void orbit_pu(int g, int& p, int& u) {
    int off = (g < 4) ? 0 : (g < 32) ? 4 : (g < 256) ? 32 : 256;
    int C   = (g < 4) ? 8 : (g < 32) ? 71 : (g < 256) ? 575 : 4607;
    p = g + off;
    u = C - p;
}

// orbit conv in storage order: pa/pb lane-contiguous -> conflict-free b128 LDS,
// HFp pair-layout -> coalesced float4 H loads, twiddle from OT[p].
__device__ __forceinline__ void orbit_conv2(float2* Z, const float2* __restrict__ HFp,
                                            const float2* __restrict__ T, int g)
{
    int p, u; orbit_pu(g, p, u);
    const int pa = 2 * p + ((p >> 3) << 1);   // PD2(2p)
    const int pb = 2 * u + ((u >> 3) << 1);   // PD2(2u)
    float4 Af = *(const float4*)&Z[pa];
    float4 Bf = *(const float4*)&Z[pb];
    float2 Sq  = make_float2(Af.x + Af.z, Af.y + Af.w);   // S[q],       q = P2h(p)
    float2 Sq4 = make_float2(Af.x - Af.z, Af.y - Af.w);   // S[q+4096]
    float2 Sk2 = make_float2(Bf.x + Bf.z, Bf.y + Bf.w);   // S[4096-q]
    float2 Smq = make_float2(Bf.x - Bf.z, Bf.y - Bf.w);   // S[8192-q]
    float2 cs = T[OTB + p];                               // e^{-2pi i q/16384}
    float4 Hq = *(const float4*)&HFp[2 * p];              // H[q], H[8192-q]
    float4 Hu = *(const float4*)&HFp[2 * u];              // H[4096-q], H[4096+q]
    float2 sp_q, sp_mq, sp_k2, sp_mk2;
    umr(Sq,  Smq,  cs.x,  cs.y, make_float2(Hq.x, Hq.y), make_float2(Hq.z, Hq.w), sp_q,  sp_mq);
    umr(Sk2, Sq4, -cs.y, -cs.x, make_float2(Hu.x, Hu.y), make_float2(Hu.z, Hu.w), sp_k2, sp_mk2);
    float4 oa, ob;
    oa.x = sp_q.x + sp_mk2.x; oa.y = sp_q.y + sp_mk2.y;
    oa.z = sp_q.x - sp_mk2.x; oa.w = sp_q.y - sp_mk2.y;
    ob.x = sp_k2.x + sp_mq.x; ob.y = sp_k2.y + sp_mq.y;
    ob.z = sp_k2.x - sp_mq.x; ob.w = sp_k2.y - sp_mq.y;
    *(float4*)&Z[pa] = oa;
    *(float4*)&Z[pb] = ob;
}

__device__ __forceinline__ void orbit_filter2(float2* Z, float2* __restrict__ out,
                                              const float2* __restrict__ T, int g)
{
    int p, u; orbit_pu(g, p, u);
    const int pa = 2 * p + ((p >> 3) << 1);
    const int pb = 2 * u + ((u >> 3) << 1);
    float4 Af = *(const float4*)&Z[pa];
    float4 Bf = *(const float4*)&Z[pb];
    float2 Sq  = make_float2(Af.x + Af.z, Af.y + Af.w);
    float2 Sq4 = make_float2(Af.x - Af.z, Af.y - Af.w);
    float2 Sk2 = make_float2(Bf.x + Bf.z, Bf.y + Bf.w);
    float2 Smq = make_float2(Bf.x - Bf.z, Bf.y - Bf.w);
    float2 cs = T[OTB + p];
    float2 Xa, Xb, Xc, Xd;
    unt2(Sq,  Smq,  cs.x,  cs.y, Xa, Xb);    // X[q], X[8192-q]
    unt2(Sk2, Sq4, -cs.y, -cs.x, Xc, Xd);    // X[4096-q], X[4096+q]
    *(float4*)&out[2 * p] = make_float4(Xa.x, Xa.y, Xb.x, Xb.y);
    *(float4*)&out[2 * u] = make_float4(Xc.x, Xc.y, Xd.x, Xd.y);
}

// ---------------------------------------------------------------------------
// twiddle-table init (writes into d_out scratch; gemm_out_k overwrites later)
// ---------------------------------------------------------------------------
__global__ __launch_bounds__(256) void tw_init(float2* __restrict__ T)
{
    const int id = blockIdx.x * 256 + threadIdx.x;
    if (id < 1170) {
        int M, k, base;
        if (id < 1024)      { M = 8192; k = id;        base = TW0 + k * 8; }
        else if (id < 1152) { M = 1024; k = id - 1024; base = TW1 + k * 8; }
        else if (id < 1168) { M = 128;  k = id - 1152; base = TW2 + k * 8; }
        else                { M = 16;   k = id - 1168; base = TW3 + k * 8; }
#pragma unroll
        for (int j = 0; j < 8; ++j) {
            float ang = -6.283185307179586f * (float)(j * k) / (float)M;
            float s, c;
            __sincosf(ang, &s, &c);
            T[base + j] = make_float2(c, s);
        }
    } else if (id < 1170 + 2304) {
        int p = id - 1170;
        int q = P2h(p);
        float s, c;
        __sincosf(-ANGN * (float)q, &s, &c);
        T[OTB + p] = make_float2(c, s);
    }
}

// ---------------------------------------------------------------------------
// one-time dtype conversions (removes per-tile fp32->bf16 VALU from the GEMMs)
// ---------------------------------------------------------------------------
__global__ __launch_bounds__(256) void cvt_x(const float* __restrict__ x, bf16* __restrict__ xb)
{
    const size_t base = ((size_t)blockIdx.x * 256 + threadIdx.x) * 16;
    float4 a = *(const float4*)(x + base);
    float4 b = *(const float4*)(x + base + 4);
    float4 c = *(const float4*)(x + base + 8);
    float4 d = *(const float4*)(x + base + 12);
    *(short8*)(xb + base)     = pack8(a, b);
    *(short8*)(xb + base + 8) = pack8(c, d);
}

__global__ __launch_bounds__(256) void cvt_w(const float* __restrict__ inW, const float* __restrict__ outW,
                                             bf16* __restrict__ inWb, bf16* __restrict__ outWb)
{
    const int e = (blockIdx.x * 256 + threadIdx.x) * 8;
    if (e < 196608) {
        float4 a = *(const float4*)(inW + e);
        float4 b = *(const float4*)(inW + e + 4);
        *(short8*)(inWb + e) = pack8(a, b);
    } else {
        const int f = e - 196608;
        float4 a = *(const float4*)(outW + f);
        float4 b = *(const float4*)(outW + f + 4);
        *(short8*)(outWb + f) = pack8(a, b);
    }
}

// ---------------------------------------------------------------------------
// shared staging: DMA one K-chunk (64 cols bf16) of W-tile (64 rows) + A-tile
// (256 rows) into linear LDS; source address pre-swizzled so SWZ reads match.
// LDS base per call is wave-uniform; HW scatters lane i at base + i*16.
// ---------------------------------------------------------------------------
__device__ __forceinline__ void stage_gemm(
    short* sWb, short* sXb, const bf16* __restrict__ Wg, const bf16* __restrict__ Ag,
    int bn, int bm, int s, int wave, int lane)
{
    const int rsub = lane >> 3, csub = lane & 7;
    // byte offset of this lane within its 8-row group: row*128B + swizzled 16B chunk
    const int off_in = rsub * 512 + ((csub * 16) ^ (rsub << 4));
    const char* wb = (const char*)Wg;
    const char* ab = (const char*)Ag;
#pragma unroll
    for (int c = 0; c < 2; ++c) {
        const int g = wave * 2 + c;
        glds16(wb + (size_t)(bn + g * 8) * 512 + s * 128 + off_in, sWb + g * 512);
    }
#pragma unroll
    for (int c = 0; c < 8; ++c) {
        const int g = wave * 8 + c;
        glds16(ab + (size_t)(bm + g * 8) * 512 + s * 128 + off_in, sXb + g * 512);
    }
}

// ---------------------------------------------------------------------------
// GEMM A: proj[n, m] = sum_k in_W[n,k] * x[m,k] + in_b[n]   (bf16 inputs)
// double-buffered global_load_lds staging, plain __syncthreads (m97 structure)
// ---------------------------------------------------------------------------
__global__ __launch_bounds__(256, 2) void gemm_proj(
    const bf16* __restrict__ xb, const bf16* __restrict__ inWb, const float* __restrict__ inb,
    bf16* __restrict__ proj)
{
    __shared__ __align__(16) short sW[2][64 * 64];
    __shared__ __align__(16) short sX[2][256 * 64];
    const int tid = threadIdx.x;
    const int wave = tid >> 6, lane = tid & 63, quad = lane >> 4, l16 = lane & 15;
    const int id = blockIdx.x;
    const int xcd = id & 7, chunk = id >> 3;
    const int bn = (chunk % 12) * 64;
    const int bm = ((chunk / 12) * 8 + xcd) * 256;

    floatx4 acc[4][4];
#pragma unroll
    for (int i = 0; i < 4; ++i)
#pragma unroll
        for (int j = 0; j < 4; ++j) acc[i][j] = (floatx4){0.f, 0.f, 0.f, 0.f};

    stage_gemm(sW[0], sX[0], inWb, xb, bn, bm, 0, wave, lane);
    for (int s = 0; s < 4; ++s) {
        const int cur = s & 1;
        if (s < 3)
            stage_gemm(sW[cur ^ 1], sX[cur ^ 1], inWb, xb, bn, bm, s + 1, wave, lane);
        __syncthreads();   // compiler-emitted vmcnt(0) drain + barrier: both buffers' DMAs done
        const short* sWc = sW[cur];
        const short* sXc = sX[cur];
#pragma unroll
        for (int kk = 0; kk < 64; kk += 32) {
            const int ko = kk + quad * 8;
            short8 wf[4], xf[4];
#pragma unroll
            for (int ts = 0; ts < 4; ++ts)
                wf[ts] = *(const short8*)(&sWc[SWZ(ts * 16 + l16, ko)]);
#pragma unroll
            for (int tb = 0; tb < 4; ++tb)
                xf[tb] = *(const short8*)(&sXc[SWZ(wave * 64 + tb * 16 + l16, ko)]);
#pragma unroll
            for (int ts = 0; ts < 4; ++ts)
#pragma unroll
                for (int tb = 0; tb < 4; ++tb)
                    acc[ts][tb] = __builtin_amdgcn_mfma_f32_16x16x32_bf16(
                        wf[ts], xf[tb], acc[ts][tb], 0, 0, 0);
        }
        __syncthreads();   // all reads of buf cur done before next iter overwrites it
    }
    // epilogue: stage [64 ch][256 m] bf16 tile in LDS (rows padded to 264 shorts
    // to break the quad-stride bank conflict), then fully-coalesced 16B stores.
    short* sE = (short*)sX;   // 64 KB free after main loop (33792 B needed)
#pragma unroll
    for (int ts = 0; ts < 4; ++ts) {
#pragma unroll
        for (int r = 0; r < 4; ++r) {
            const int ch = ts * 16 + quad * 4 + r;
            const float bias = inb[bn + ch];
#pragma unroll
            for (int tb = 0; tb < 4; ++tb) {
                const int m = wave * 64 + tb * 16 + l16;
                sE[ch * 264 + m] = f2bs(acc[ts][tb][r] + bias);
            }
        }
    }
    __syncthreads();
    const int seg = bn >> 8;
    const int bb = bm >> 13;
    const int cbase = bn & 255;
    const int lbase = bm & 8191;
#pragma unroll
    for (int it = 0; it < 8; ++it) {
        const int idx = it * 256 + tid;
        const int ch = idx >> 5, ck = idx & 31;
        uint4 v = *(const uint4*)(sE + ch * 264 + ck * 8);
        *(uint4*)((char*)proj + ((size_t)(seg * 2048 + bb * 256 + cbase + ch) * 8192 + lbase) * 2 + ck * 16) = v;
    }
}

// ---------------------------------------------------------------------------
// GEMM F: out[m, n] = sum_k gated[m,k] * out_W[n,k] + out_b[n]  (bf16 inputs)
// ---------------------------------------------------------------------------
__global__ __launch_bounds__(256, 2) void gemm_out_k(
    const bf16* __restrict__ gated, const bf16* __restrict__ outWb, const float* __restrict__ outb,
    float* __restrict__ out)
{
    __shared__ __align__(16) short sW[2][64 * 64];
    __shared__ __align__(16) short sA[2][256 * 64];
    const int tid = threadIdx.x;
    const int wave = tid >> 6, lane = tid & 63, quad = lane >> 4, l16 = lane & 15;
    const int id = blockIdx.x;
    const int xcd = id & 7, chunk = id >> 3;
    const int bn = (chunk & 3) * 64;
    const int bm = ((chunk >> 2) * 8 + xcd) * 256;

    floatx4 acc[4][4];
#pragma unroll
    for (int i = 0; i < 4; ++i)
#pragma unroll
        for (int j = 0; j < 4; ++j) acc[i][j] = (floatx4){0.f, 0.f, 0.f, 0.f};

    stage_gemm(sW[0], sA[0], outWb, gated, bn, bm, 0, wave, lane);
    for (int s = 0; s < 4; ++s) {
        const int cur = s & 1;
        if (s < 3)
            stage_gemm(sW[cur ^ 1], sA[cur ^ 1], outWb, gated, bn, bm, s + 1, wave, lane);
        __syncthreads();
        const short* sWc = sW[cur];
        const short* sAc = sA[cur];
#pragma unroll
        for (int kk = 0; kk < 64; kk += 32) {
            const int ko = kk + quad * 8;
            short8 bfr[4], af[4];
#pragma unroll
            for (int ts = 0; ts < 4; ++ts)
                bfr[ts] = *(const short8*)(&sWc[SWZ(ts * 16 + l16, ko)]);
#pragma unroll
            for (int tb = 0; tb < 4; ++tb)
                af[tb] = *(const short8*)(&sAc[SWZ(wave * 64 + tb * 16 + l16, ko)]);
#pragma unroll
            for (int tb = 0; tb < 4; ++tb)
#pragma unroll
                for (int ts = 0; ts < 4; ++ts)
                    acc[tb][ts] = __builtin_amdgcn_mfma_f32_16x16x32_bf16(
                        af[tb], bfr[ts], acc[tb][ts], 0, 0, 0);
        }
        __syncthreads();
    }
#pragma unroll
    for (int tb = 0; tb < 4; ++tb) {
#pragma unroll
        for (int r = 0; r < 4; ++r) {
            const int m = bm + wave * 64 + tb * 16 + quad * 4 + r;
#pragma unroll
            for (int ts = 0; ts < 4; ++ts) {
                const int n = bn + ts * 16 + l16;
                out[(size_t)m * 256 + n] = acc[tb][ts][r] + outb[n];
            }
        }
    }
}

// ---------------------------------------------------------------------------
// h[d, l] = silu(t_l*W1 + b1) @ W2[d,:] + b2[d]   (all fp32)
// ---------------------------------------------------------------------------
__global__ __launch_bounds__(256) void build_h(
    const float* __restrict__ tpos, const float* __restrict__ W1, const float* __restrict__ b1,
    const float* __restrict__ W2, const float* __restrict__ b2, float* __restrict__ h)
{
    __shared__ float s[32][64];
    __shared__ float tr[256 * 32];
    const int tid = threadIdx.x;
    const int l0 = blockIdx.x * 32;
#pragma unroll
    for (int p = 0; p < 8; ++p) {
        int idx = tid + p * 256;
        int li = idx >> 6, j = idx & 63;
        float tv = tpos[l0 + li];
        float z = tv * W1[j] + b1[j];
        s[li][j] = z / (1.f + __expf(-z));
    }
    __syncthreads();
    const int d = tid;
    float acc[32];
    float bb = b2[d];
#pragma unroll
    for (int li = 0; li < 32; ++li) acc[li] = bb;
    for (int j = 0; j < 64; ++j) {
        float w = W2[d * 64 + j];
#pragma unroll
        for (int li = 0; li < 32; ++li) acc[li] += w * s[li][j];
    }
#pragma unroll
    for (int li = 0; li < 32; ++li) tr[d * 32 + li] = acc[li];
    __syncthreads();
#pragma unroll
    for (int p = 0; p < 8; ++p) {
        int idx = tid + p * 256;
        int row = idx >> 3, c = (idx & 7) * 4;
        *(float4*)(h + (size_t)row * 8192 + l0 + c) = *(const float4*)(&tr[row * 32 + c]);
    }
}

// ---------------------------------------------------------------------------
// hf (pair layout): HFp[2p]=X[P2h(p)], HFp[2p+1]=X[8192-P2h(p)]; HFp[8192]=X[4096]
// ---------------------------------------------------------------------------
__global__ __launch_bounds__(1024, 8) void fft_filter(
    const float* __restrict__ h, float2* __restrict__ hf, const float2* __restrict__ T)
{
    __shared__ __align__(16) float2 Z[9216];
    const int d = blockIdx.x;
    const int t = threadIdx.x;
    const float2* hrow = (const float2*)(h + (size_t)d * L_SZ);
    // fused first stage (M=8192): inputs j>=4 are zero
    {
        const int b0 = PD2(t);
        float xr[8], xi[8];
#pragma unroll
        for (int j = 0; j < 4; ++j) { float2 z = hrow[t + (j << 10)]; xr[j] = z.x; xi[j] = z.y; }
#pragma unroll
        for (int j = 4; j < 8; ++j) { xr[j] = 0.f; xi[j] = 0.f; }
        float yr[8], yi[8];
        dft8<-1>(xr, xi, yr, yi);
        twmul_fwd(T + TW0 + t * 8, yr, yi);
#pragma unroll
        for (int j = 0; j < 8; ++j) Z[b0 + j * 1152] = make_float2(yr[j], yi[j]);
    }
    __syncthreads();
    s8f<1024, TW1>(Z, t, T); __syncthreads();
    s8f<128,  TW2>(Z, t, T); __syncthreads();
    s8f<16,   TW3>(Z, t, T); __syncthreads();
    float2* outp = hf + (size_t)d * HFS;
    if (t == 0) {
        float4 Af = *(const float4*)&Z[0];
        float2 S0 = make_float2(Af.x + Af.z, Af.y + Af.w);
        float2 S4 = make_float2(Af.x - Af.z, Af.y - Af.w);
        outp[0]    = make_float2(S0.x + S0.y, 0.f);   // X[0]
        outp[1]    = make_float2(S0.x - S0.y, 0.f);   // X[8192]
        outp[8192] = make_float2(S4.x, -S4.y);        // X[4096]
        float4 Bf = *(const float4*)&Z[8];            // p=4 degenerate orbit (q=2048)
        float2 S2k = make_float2(Bf.x + Bf.z, Bf.y + Bf.w);
        float2 S6k = make_float2(Bf.x - Bf.z, Bf.y - Bf.w);
        const float R2 = 0.70710678118654752f;
        float2 Xa, Xb;
        unt2(S2k, S6k, R2, -R2, Xa, Xb);
        outp[8] = Xa; outp[9] = Xb;                   // X[2048], X[6144]
    } else {
        orbit_filter2(Z, outp, T, t);
    }
    orbit_filter2(Z, outp, T, t + 1024);
}

// ---------------------------------------------------------------------------
// per (b,d): y = irfft(rfft(v)*hf[d])[:L]; gate with both dwconvs; write gatedT
// ---------------------------------------------------------------------------
__global__ __launch_bounds__(1024, 8) void fft_conv(
    const bf16* __restrict__ proj, const float2* __restrict__ hf, const float2* __restrict__ T,
    const float* __restrict__ cw0, const float* __restrict__ cb0,
    const float* __restrict__ cw1, const float* __restrict__ cb1,
    bf16* __restrict__ gatedT)
{
    __shared__ __align__(16) float2 Z[9216];
    const int bid = blockIdx.x;
    // XCD-affine: the 8 batch-blocks sharing hf[d] land on the same XCD (bid%8 fixed)
    const int d = ((bid >> 6) << 3) | (bid & 7);
    const int b = (bid >> 3) & 7;
    const int t = threadIdx.x;
    const size_t rowoff = ((size_t)(b * 256 + d)) * L_SZ;
    // fused first stage: bf16 v row -> complex packed, upper half zero
    {
        const unsigned int* vrow = (const unsigned int*)(proj + rowoff);
        const int b0 = PD2(t);
        float xr[8], xi[8];
#pragma unroll
        for (int j = 0; j < 4; ++j) {
            unsigned int u = vrow[t + (j << 10)];
            xr[j] = lo2f(u); xi[j] = hi2f(u);
        }
#pragma unroll
        for (int j = 4; j < 8; ++j) { xr[j] = 0.f; xi[j] = 0.f; }
        float yr[8], yi[8];
        dft8<-1>(xr, xi, yr, yi);
        twmul_fwd(T + TW0 + t * 8, yr, yi);
#pragma unroll
        for (int j = 0; j < 8; ++j) Z[b0 + j * 1152] = make_float2(yr[j], yi[j]);
    }
    __syncthreads();
    s8f<1024, TW1>(Z, t, T); __syncthreads();
    s8f<128,  TW2>(Z, t, T); __syncthreads();
    s8f<16,   TW3>(Z, t, T); __syncthreads();
    const float2* H = hf + (size_t)d * HFS;
    if (t == 0) {
        // orbit {0, 4096}
        float4 Af = *(const float4*)&Z[0];
        float2 S0 = make_float2(Af.x + Af.z, Af.y + Af.w);
        float2 S4 = make_float2(Af.x - Af.z, Af.y - Af.w);
        float x0 = S0.x + S0.y, xm = S0.x - S0.y;
        float2 H0 = H[0], Hm = H[1], H4 = H[8192];
        float y0r = x0 * H0.x, y0i = x0 * H0.y;
        float ymr = xm * Hm.x, ymi = xm * Hm.y;
        float yer = 0.5f*(y0r + ymr), yei = 0.5f*(y0i + ymi);
        float yor = 0.5f*(y0r - ymr), yoi = 0.5f*(y0i - ymi);
        float2 spdc = make_float2(yer - yoi, yei + yor);
        float y4r = S4.x * H4.x + S4.y * H4.y;
        float y4i = S4.x * H4.y - S4.y * H4.x;
        float2 sp4 = make_float2(y4r, -y4i);
        Z[0] = make_float2(spdc.x + sp4.x, spdc.y + sp4.y);
        Z[1] = make_float2(spdc.x - sp4.x, spdc.y - sp4.y);
        // p=4 degenerate orbit {2048, 6144}
        float4 Bf = *(const float4*)&Z[8];
        float2 S2k = make_float2(Bf.x + Bf.z, Bf.y + Bf.w);
        float2 S6k = make_float2(Bf.x - Bf.z, Bf.y - Bf.w);
        const float R2 = 0.70710678118654752f;
        float2 spa, spb;
        umr(S2k, S6k, R2, -R2, H[8], H[9], spa, spb);
        Z[8] = make_float2(spa.x + spb.x, spa.y + spb.y);
        Z[9] = make_float2(spa.x - spb.x, spa.y - spb.y);
    } else {
        orbit_conv2(Z, H, T, t);
    }
    orbit_conv2(Z, H, T, t + 1024);
    __syncthreads();
    s8i<16,   TW3>(Z, t, T); __syncthreads();
    s8i<128,  TW2>(Z, t, T); __syncthreads();
    s8i<1024, TW1>(Z, t, T); __syncthreads();
    // fused final inverse stage (M=8192) + gating epilogue
    const int b0 = PD2(t);
    float xr[8], xi[8];
#pragma unroll
    for (int j = 0; j < 8; ++j) { float2 z = Z[b0 + j * 1152]; xr[j] = z.x; xi[j] = z.y; }
    twmul_inv(T + TW0 + t * 8, xr, xi);
    float yr[8], yi[8];
    dft8<1>(xr, xi, yr, yi);
    const float sc = 1.0f / 8192.0f;
    const float w00 = cw0[d * 3], w01 = cw0[d * 3 + 1], w02 = cw0[d * 3 + 2], bi0 = cb0[d];
    const float w10 = cw1[d * 3], w11 = cw1[d * 3 + 1], w12 = cw1[d * 3 + 2], bi1 = cb1[d];
    const unsigned int* R0 = (const unsigned int*)(proj + (size_t)2048 * L_SZ + rowoff);
    const unsigned int* R1 = (const unsigned int*)(proj + (size_t)4096 * L_SZ + rowoff);
    unsigned int* gout = (unsigned int*)gatedT + ((size_t)d * 32768 + b * 4096);
#pragma unroll
    for (int j = 0; j < 4; ++j) {
        const int n = t + (j << 10);
        const float v0 = yr[j] * sc;
        const float v1 = yi[j] * sc;
        unsigned int m0u = (n > 0) ? R0[n - 1] : 0u;
        unsigned int c0u = R0[n];
        unsigned int p0u = (n < 4095) ? R0[n + 1] : 0u;
        unsigned int m1u = (n > 0) ? R1[n - 1] : 0u;
        unsigned int c1u = R1[n];
        unsigned int p1u = (n < 4095) ? R1[n + 1] : 0u;
        float g00 = w00 * hi2f(m0u) + w01 * lo2f(c0u) + w02 * hi2f(c0u) + bi0;
        float g01 = w00 * lo2f(c0u) + w01 * hi2f(c0u) + w02 * lo2f(p0u) + bi0;
        float g10 = w10 * hi2f(m1u) + w11 * lo2f(c1u) + w12 * hi2f(c1u) + bi1;
        float g11 = w10 * lo2f(c1u) + w11 * hi2f(c1u) + w12 * lo2f(p1u) + bi1;
        unsigned int o = (unsigned int)f2bu(v0 * g00 * g10)
                       | ((unsigned int)f2bu(v1 * g01 * g11) << 16);
        gout[n] = o;
    }
}

// ---------------------------------------------------------------------------
// gatedT[256][65536] -> gated[65536][256]  (bf16 transpose, 64x64 tiles)
// ---------------------------------------------------------------------------
__global__ __launch_bounds__(256) void transpose_k(
    const ushort* __restrict__ gatedT, ushort* __restrict__ gated)
{
    __shared__ ushort T2[64 * 66];
    const int tid = threadIdx.x;
    const int m0 = blockIdx.x * 64, d0 = blockIdx.y * 64;
    const int rr = tid >> 3, co = (tid & 7) * 8;
#pragma unroll
    for (int it = 0; it < 2; ++it) {
        const int dr = rr + 32 * it;
        const uint4 val = *(const uint4*)(gatedT + (size_t)(d0 + dr) * 65536 + m0 + co);
        const ushort* vs = (const ushort*)&val;
#pragma unroll
        for (int i = 0; i < 8; ++i)
            T2[(co + i) * 66 + dr] = vs[i];
    }
    __syncthreads();
#pragma unroll
    for (int it = 0; it < 2; ++it) {
        const int mr = rr + 32 * it;
        uint w0 = *(const uint*)(T2 + mr * 66 + co);
        uint w1 = *(const uint*)(T2 + mr * 66 + co + 2);
        uint w2 = *(const uint*)(T2 + mr * 66 + co + 4);
        uint w3 = *(const uint*)(T2 + mr * 66 + co + 6);
        uint4 ov; ov.x = w0; ov.y = w1; ov.z = w2; ov.w = w3;
        *(uint4*)(gated + (size_t)(m0 + mr) * 256 + d0 + co) = ov;
    }
}

// ---------------------------------------------------------------------------
extern "C" void kernel_launch(void* const* d_in, const int* in_sizes, int n_in,
                              void* d_out, int out_size, void* d_ws, size_t ws_size,
                              hipStream_t stream)
{
    const float* x    = (const float*)d_in[0];
    const float* inW  = (const float*)d_in[1];
    const float* inb  = (const float*)d_in[2];
    const float* c0W  = (const float*)d_in[3];
    const float* c0b  = (const float*)d_in[4];
    const float* c1W  = (const float*)d_in[5];
    const float* c1b  = (const float*)d_in[6];
    const float* mW1  = (const float*)d_in[7];
    const float* mb1  = (const float*)d_in[8];
    const float* mW2  = (const float*)d_in[9];
    const float* mb2  = (const float*)d_in[10];
    const float* oW   = (const float*)d_in[11];
    const float* ob   = (const float*)d_in[12];
    const float* tpos = (const float*)d_in[13];
    float* out = (float*)d_out;

    char* ws = (char*)d_ws;
    // ws: persistent intermediates (~176.7 MB, below previously-verified 193 MB)
    bf16*   proj   = (bf16*)(ws);                    // 96 MB [3][2048][8192]: v, raw0, raw1
    bf16*   gatedT = (bf16*)(ws + 100663296);        // 32 MB [256][65536]
    bf16*   gated  = (bf16*)(ws + 134217728);        // 32 MB [65536][256]
    float*  h      = (float*)(ws + 167772160);       // 8 MB [256][8192]
    bf16*   inWb   = (bf16*)(ws + 176160768);        // 384 KB [768][256] bf16 in_W
    bf16*   outWb  = (bf16*)(ws + 176553984);        // 128 KB [256][256] bf16 out_W (ws, NOT d_out: read while out is written)
    // d_out scratch: everything here is consumed strictly before gemm_out_k writes out
    float2* T  = (float2*)d_out;                                   // ~93 KB tables
    float2* hf = (float2*)((char*)d_out + HF_BYTE_OFF);            // 16.78 MB [256][HFS]
    bf16*   xb = (bf16*)((char*)d_out + XB_BYTE_OFF);              // 32 MB [65536][256] bf16 x

    cvt_w<<<128, 256, 0, stream>>>(inW, oW, inWb, outWb);
    cvt_x<<<4096, 256, 0, stream>>>(x, xb);
    tw_init<<<14, 256, 0, stream>>>(T);
    build_h<<<256, 256, 0, stream>>>(tpos, mW1, mb1, mW2, mb2, h);
    fft_filter<<<256, 1024, 0, stream>>>(h, hf, T);
    gemm_proj<<<3072, 256, 0, stream>>>(xb, inWb, inb, proj);
    fft_conv<<<2048, 1024, 0, stream>>>(proj, hf, T, c0W, c0b, c1W, c1b, gatedT);
    transpose_k<<<dim3(1024, 4), 256, 0, stream>>>((const ushort*)gatedT, (ushort*)gated);
    gemm_out_k<<<1024, 256, 0, stream>>>(gated, outWb, ob, out);
}